// Round 1
// 180.404 us; speedup vs baseline: 1.0393x; 1.0393x over previous
//
#include <hip/hip_runtime.h>
#include <math.h>

#define NSTATE 64
#define LEN    4096
#define NH     256
#define NB     16

// K in base-8 digit-reversed order (fftconv consumption order).
// Position p holds natural frequency rev8_12(p) (rev8_12 is an involution).
__device__ float2 g_ksym[NH * LEN];
// per-(h,n) Cauchy params: A={lam_r,lam_i,|P|^2,pad} B={v0r,v0i,v1r,v1i} C={v2r,v2i}
__device__ float4 g_pA[NH * NSTATE];
__device__ float4 g_pB[NH * NSTATE];
__device__ float2 g_pC[NH * NSTATE];

__device__ __forceinline__ int rev8_12(int p) {
  return ((p & 7) << 9) | (((p >> 3) & 7) << 6) | (((p >> 6) & 7) << 3) | (p >> 9);
}

// ---------------- complex helpers ----------------
__device__ __forceinline__ float2 cadd(float2 a, float2 b){ return make_float2(a.x+b.x, a.y+b.y); }
__device__ __forceinline__ float2 csub(float2 a, float2 b){ return make_float2(a.x-b.x, a.y-b.y); }
__device__ __forceinline__ float2 cmul(float2 a, float2 b){ return make_float2(a.x*b.x - a.y*b.y, a.x*b.y + a.y*b.x); }
__device__ __forceinline__ float2 mulnegi(float2 a){ return make_float2(a.y, -a.x); }
__device__ __forceinline__ float2 mulposi(float2 a){ return make_float2(-a.y, a.x); }

#define RSQ2 0.70710678118654752f

__device__ __forceinline__ void bfly8_fwd(float2 v[8]) {
  float2 a0 = cadd(v[0], v[4]), b0 = csub(v[0], v[4]);
  float2 a1 = cadd(v[1], v[5]), d1 = csub(v[1], v[5]);
  float2 a2 = cadd(v[2], v[6]), d2 = csub(v[2], v[6]);
  float2 a3 = cadd(v[3], v[7]), d3 = csub(v[3], v[7]);
  float2 b1 = make_float2(RSQ2 * (d1.x + d1.y), RSQ2 * (d1.y - d1.x));
  float2 b2 = mulnegi(d2);
  float2 b3 = make_float2(RSQ2 * (d3.y - d3.x), -RSQ2 * (d3.x + d3.y));
  float2 u0 = cadd(a0, a2), u1 = csub(a0, a2), u2 = cadd(a1, a3), u3 = csub(a1, a3);
  v[0] = cadd(u0, u2);
  v[2] = cadd(u1, mulnegi(u3));
  v[4] = csub(u0, u2);
  v[6] = cadd(u1, mulposi(u3));
  float2 w0 = cadd(b0, b2), w1 = csub(b0, b2), w2 = cadd(b1, b3), w3 = csub(b1, b3);
  v[1] = cadd(w0, w2);
  v[3] = cadd(w1, mulnegi(w3));
  v[5] = csub(w0, w2);
  v[7] = cadd(w1, mulposi(w3));
}

__device__ __forceinline__ void bfly8_inv(float2 v[8]) {
  float2 a0 = cadd(v[0], v[4]), b0 = csub(v[0], v[4]);
  float2 a1 = cadd(v[1], v[5]), d1 = csub(v[1], v[5]);
  float2 a2 = cadd(v[2], v[6]), d2 = csub(v[2], v[6]);
  float2 a3 = cadd(v[3], v[7]), d3 = csub(v[3], v[7]);
  float2 b1 = make_float2(RSQ2 * (d1.x - d1.y), RSQ2 * (d1.x + d1.y));
  float2 b2 = mulposi(d2);
  float2 b3 = make_float2(-RSQ2 * (d3.x + d3.y), RSQ2 * (d3.x - d3.y));
  float2 u0 = cadd(a0, a2), u1 = csub(a0, a2), u2 = cadd(a1, a3), u3 = csub(a1, a3);
  v[0] = cadd(u0, u2);
  v[2] = cadd(u1, mulposi(u3));
  v[4] = csub(u0, u2);
  v[6] = cadd(u1, mulnegi(u3));
  float2 w0 = cadd(b0, b2), w1 = csub(b0, b2), w2 = cadd(b1, b3), w3 = csub(b1, b3);
  v[1] = cadd(w0, w2);
  v[3] = cadd(w1, mulposi(w3));
  v[5] = csub(w0, w2);
  v[7] = cadd(w1, mulnegi(w3));
}

__device__ __forceinline__ void twiddle7(float2 v[8], float wr, float wi) {
  float2 w1 = make_float2(wr, wi);
  float2 w2 = cmul(w1, w1);
  float2 w3 = cmul(w2, w1);
  float2 w4 = cmul(w2, w2);
  float2 w5 = cmul(w3, w2);
  float2 w6 = cmul(w3, w3);
  float2 w7 = cmul(w4, w3);
  v[1] = cmul(v[1], w1); v[2] = cmul(v[2], w2); v[3] = cmul(v[3], w3);
  v[4] = cmul(v[4], w4); v[5] = cmul(v[5], w5); v[6] = cmul(v[6], w6);
  v[7] = cmul(v[7], w7);
}

// wave-local LDS fence: all our ds_writes complete before subsequent ds_reads issue.
// "memory" clobber also pins compiler ordering of LDS accesses across the fence.
#define WAVE_SYNC() asm volatile("s_waitcnt lgkmcnt(0)" ::: "memory")

// ---------------- param precompute ----------------
__global__ __launch_bounds__(256) void s4_prep(
    const float* __restrict__ Lre, const float* __restrict__ Lim,
    const float* __restrict__ Pre, const float* __restrict__ Pim,
    const float* __restrict__ Bre, const float* __restrict__ Bim,
    const float* __restrict__ Cre, const float* __restrict__ Cim)
{
  int idx = blockIdx.x * 256 + threadIdx.x;
  if (idx >= NH * NSTATE) return;
  float lr = Lre[idx], li = Lim[idx];
  float pr = Pre[idx], pi = Pim[idx];
  float br = Bre[idx], bi = Bim[idx];
  float cr = Cre[idx], ci = Cim[idx];
  g_pA[idx] = make_float4(lr, li, pr * pr + pi * pi, 0.0f);
  g_pB[idx] = make_float4(cr * br + ci * bi, cr * bi - ci * br,
                          cr * pr + ci * pi, cr * pi - ci * pr);
  g_pC[idx] = make_float2(pr * br + pi * bi, pr * bi - pi * br);
}

// ---------------- frequency-domain S4 kernel ----------------
// Grid NH*4 blocks x 256 threads. Thread (h, q) evaluates K at 4 points:
//   A: l=q            B: mirror (4096-q)&4095   (q==0 -> l=2048, self-paired)
//   C: l=1024+q       D: mirror 3072-q
// Symmetrization done in registers via mirror pairs; writes go DIRECTLY to the
// base-8 digit-reversed positions consumed by s4_fftconv (reorder kernel fused away).
__global__ __launch_bounds__(256) void s4_kernel_freq(const float* __restrict__ log_step)
{
  const int b = blockIdx.x;
  const int h = b >> 2;
  const int q = ((b & 3) << 8) | threadIdx.x;  // 0..1023
  const float step = expf(log_step[h]);
  const float ts = 2.0f / step;
  const float NEG2PI = -6.2831853071795864769f;

  float gar, gai, car, cai, gbr, gbi, cbr, cbi;
  float gcr, gci, ccr, cci, gdr, gdi, cdr, cdi;
  {
    float so, co;
    sincosf(NEG2PI * ((float)q * (1.0f / (float)LEN)), &so, &co);
    float dr = 1.0f + co, di = so;
    float inv = 1.0f / fmaf(dr, dr, di * di);
    car = 2.0f * dr * inv; cai = -2.0f * di * inv;
    float nr = 1.0f - co, ni = -so;
    gar = ts * (fmaf(nr, dr, ni * di) * inv);
    gai = ts * (fmaf(ni, dr, -nr * di) * inv);
  }
  if (q == 0) {           // point B is l = 2048 (self-paired), compute directly
    float so, co;
    sincosf(NEG2PI * 0.5f, &so, &co);
    float dr = 1.0f + co, di = so;
    float inv = 1.0f / fmaf(dr, dr, di * di);
    cbr = 2.0f * dr * inv; cbi = -2.0f * di * inv;
    float nr = 1.0f - co, ni = -so;
    gbr = ts * (fmaf(nr, dr, ni * di) * inv);
    gbi = ts * (fmaf(ni, dr, -nr * di) * inv);
  } else {                // B = mirror of A: Omega -> conj => g,c -> conj
    gbr = gar; gbi = -gai; cbr = car; cbi = -cai;
  }
  {
    float so, co;
    sincosf(NEG2PI * ((float)(q + 1024) * (1.0f / (float)LEN)), &so, &co);
    float dr = 1.0f + co, di = so;
    float inv = 1.0f / fmaf(dr, dr, di * di);
    ccr = 2.0f * dr * inv; cci = -2.0f * di * inv;
    float nr = 1.0f - co, ni = -so;
    gcr = ts * (fmaf(nr, dr, ni * di) * inv);
    gci = ts * (fmaf(ni, dr, -nr * di) * inv);
  }
  gdr = gcr; gdi = -gci; cdr = ccr; cdi = -cci;

  float A00r=0,A00i=0,A01r=0,A01i=0,A10r=0,A10i=0,A11r=0,A11i=0;
  float B00r=0,B00i=0,B01r=0,B01i=0,B10r=0,B10i=0,B11r=0,B11i=0;
  float C00r=0,C00i=0,C01r=0,C01i=0,C10r=0,C10i=0,C11r=0,C11i=0;
  float D00r=0,D00i=0,D01r=0,D01i=0,D10r=0,D10i=0,D11r=0,D11i=0;

  const float4* __restrict__ pa = g_pA + h * NSTATE;
  const float4* __restrict__ pb = g_pB + h * NSTATE;
  const float2* __restrict__ pc = g_pC + h * NSTATE;

#define CAUCHY(gre, gim, k00r,k00i,k01r,k01i,k10r,k10i,k11r,k11i)            \
  {                                                                          \
    float rd = gre - Av.x, id = gim - Av.y;                                  \
    float idn = __builtin_amdgcn_rcpf(fmaf(rd, rd, id * id));                \
    float ir = rd * idn, ii = -(id * idn);                                   \
    k00r = fmaf(Bv.x, ir, k00r); k00r = fmaf(-Bv.y, ii, k00r);               \
    k00i = fmaf(Bv.x, ii, k00i); k00i = fmaf(Bv.y, ir, k00i);                \
    k01r = fmaf(Bv.z, ir, k01r); k01r = fmaf(-Bv.w, ii, k01r);               \
    k01i = fmaf(Bv.z, ii, k01i); k01i = fmaf(Bv.w, ir, k01i);                \
    k10r = fmaf(Cv.x, ir, k10r); k10r = fmaf(-Cv.y, ii, k10r);               \
    k10i = fmaf(Cv.x, ii, k10i); k10i = fmaf(Cv.y, ir, k10i);                \
    k11r = fmaf(Av.z, ir, k11r); k11i = fmaf(Av.z, ii, k11i);                \
  }

#pragma unroll 4
  for (int n = 0; n < NSTATE; ++n) {
    float4 Av = pa[n];
    float4 Bv = pb[n];
    float2 Cv = pc[n];
    CAUCHY(gar, gai, A00r,A00i,A01r,A01i,A10r,A10i,A11r,A11i)
    CAUCHY(gbr, gbi, B00r,B00i,B01r,B01i,B10r,B10i,B11r,B11i)
    CAUCHY(gcr, gci, C00r,C00i,C01r,C01i,C10r,C10i,C11r,C11i)
    CAUCHY(gdr, gdi, D00r,D00i,D01r,D01i,D10r,D10i,D11r,D11i)
  }
#undef CAUCHY

#define FINISH(cr_, ci_, k00r,k00i,k01r,k01i,k10r,k10i,k11r,k11i, Kr, Ki)    \
  {                                                                          \
    float rr = 1.0f + k11r, ri = k11i;                                       \
    float rinv = 1.0f / fmaf(rr, rr, ri * ri);                               \
    float pr_ = k01r * k10r - k01i * k10i;                                   \
    float pi_ = k01r * k10i + k01i * k10r;                                   \
    float wr = (pr_ * rr + pi_ * ri) * rinv;                                 \
    float wi = (pi_ * rr - pr_ * ri) * rinv;                                 \
    float sr = k00r - wr, si = k00i - wi;                                    \
    Kr = cr_ * sr - ci_ * si; Ki = cr_ * si + ci_ * sr;                      \
  }

  float Kar, Kai, Kbr, Kbi, Kcr, Kci, Kdr, Kdi;
  FINISH(car, cai, A00r,A00i,A01r,A01i,A10r,A10i,A11r,A11i, Kar, Kai)
  FINISH(cbr, cbi, B00r,B00i,B01r,B01i,B10r,B10i,B11r,B11i, Kbr, Kbi)
  FINISH(ccr, cci, C00r,C00i,C01r,C01i,C10r,C10i,C11r,C11i, Kcr, Kci)
  FINISH(cdr, cdi, D00r,D00i,D01r,D01i,D10r,D10i,D11r,D11i, Kdr, Kdi)
#undef FINISH

  float2* out = g_ksym + (size_t)h * LEN;
  if (q == 0) {
    out[rev8_12(0)]    = make_float2(Kar, 0.0f);   // Ksym[0]    = Re K[0]
    out[rev8_12(2048)] = make_float2(Kbr, 0.0f);   // Ksym[2048] = Re K[2048]
  } else {
    float fr = 0.5f * (Kar + Kbr), fi = 0.5f * (Kai - Kbi);
    out[rev8_12(q)]       = make_float2(fr, fi);
    out[rev8_12(LEN - q)] = make_float2(fr, -fi);  // conj pair
  }
  {
    float fr = 0.5f * (Kcr + Kdr), fi = 0.5f * (Kci - Kdi);
    out[rev8_12(1024 + q)] = make_float2(fr, fi);
    out[rev8_12(3072 - q)] = make_float2(fr, -fi);
  }
}

// ---------------- FFT convolution: register radix-8, 4096 = 8^4 ----------------
// Wave-local schedule: after the block-wide stride-512 stage, each of the 8 waves
// owns one independent 512-point sub-FFT in a private 576-float2 LDS region
// (same in-region padded layouts as before -> same bank behavior). Only TWO
// block barriers remain (scatter after stage 1, gather before inverse stage 1);
// all interior stage handoffs are wave-local s_waitcnt lgkmcnt(0) fences.
__global__ __launch_bounds__(512) void s4_fftconv(const float* __restrict__ u,
                                                 float* __restrict__ y)
{
  __shared__ float2 X[4608];   // 8 waves x 576

  const int t = threadIdx.x;
  const int bid = blockIdx.x;
  const int h  = bid & (NH - 1);
  const int bp = bid >> 8;

  const int w  = t >> 6;        // wave id == radix-8 stage-1 output digit r1
  const int i  = t & 63;        // lane within wave
  const int i3 = i >> 3;
  const int i7 = i & 7;
  const int R  = 576 * w;       // private LDS region base

  float c1, s1, c2, s2, c3, s3;
  sincosf((float)t  * (-6.2831853071795864769f / 4096.0f), &s1, &c1);
  sincosf((float)i  * (-6.2831853071795864769f /  512.0f), &s2, &c2);
  sincosf((float)i7 * (-6.2831853071795864769f /   64.0f), &s3, &c3);

  const float* u1 = u + ((size_t)bp * NH + h) * LEN;
  const float* u2 = u + ((size_t)(bp + 8) * NH + h) * LEN;

  float2 v[8];
#pragma unroll
  for (int m = 0; m < 8; ++m)
    v[m] = make_float2(u1[t + 512 * m], u2[t + 512 * m]);
  bfly8_fwd(v);
  twiddle7(v, c1, s1);
#pragma unroll
  for (int m = 0; m < 8; ++m) X[576 * m + t] = v[m];   // scatter: group m region
  __syncthreads();                                     // block barrier #1

  // ---- stage 2 (stride 64 within group), wave-local from here ----
#pragma unroll
  for (int m = 0; m < 8; ++m) v[m] = X[R + i + 64 * m];
  bfly8_fwd(v);
  twiddle7(v, c2, s2);
#pragma unroll
  for (int m = 0; m < 8; ++m) X[R + 68 * m + i] = v[m];
  WAVE_SYNC();

  // ---- stage 3 (stride 8) ----
#pragma unroll
  for (int m = 0; m < 8; ++m) v[m] = X[R + 68 * i3 + i7 + 8 * m];
  bfly8_fwd(v);
  twiddle7(v, c3, s3);
#pragma unroll
  for (int m = 0; m < 8; ++m) X[R + 9 * (8 * i3 + m) + i7] = v[m];
  WAVE_SYNC();

  // ---- stage 4 fwd + pointwise + stage 4 inv (registers) ----
  {
    const float4* kp = (const float4*)(g_ksym + (size_t)h * LEN + 8 * t);
    float4 k0 = kp[0], k1 = kp[1], k2 = kp[2], k3 = kp[3];
#pragma unroll
    for (int m = 0; m < 8; ++m) v[m] = X[R + 9 * i + m];
    bfly8_fwd(v);
    v[0] = cmul(v[0], make_float2(k0.x, k0.y));
    v[1] = cmul(v[1], make_float2(k0.z, k0.w));
    v[2] = cmul(v[2], make_float2(k1.x, k1.y));
    v[3] = cmul(v[3], make_float2(k1.z, k1.w));
    v[4] = cmul(v[4], make_float2(k2.x, k2.y));
    v[5] = cmul(v[5], make_float2(k2.z, k2.w));
    v[6] = cmul(v[6], make_float2(k3.x, k3.y));
    v[7] = cmul(v[7], make_float2(k3.z, k3.w));
    bfly8_inv(v);
#pragma unroll
    for (int p = 0; p < 8; ++p) X[R + 9 * i + p] = v[p];
  }
  WAVE_SYNC();

  // ---- stage 3 inverse ----
#pragma unroll
  for (int m = 0; m < 8; ++m) v[m] = X[R + 9 * (8 * i3 + m) + i7];
  twiddle7(v, c3, -s3);
  bfly8_inv(v);
#pragma unroll
  for (int p = 0; p < 8; ++p) X[R + 68 * i3 + i7 + 8 * p] = v[p];
  WAVE_SYNC();

  // ---- stage 2 inverse ----
#pragma unroll
  for (int m = 0; m < 8; ++m) v[m] = X[R + 68 * m + i];
  twiddle7(v, c2, -s2);
  bfly8_inv(v);
#pragma unroll
  for (int p = 0; p < 8; ++p) X[R + i + 64 * p] = v[p];
  __syncthreads();                                     // block barrier #2

  // ---- stage 1 inverse (block-wide gather) ----
#pragma unroll
  for (int m = 0; m < 8; ++m) v[m] = X[576 * m + t];
  twiddle7(v, c1, -s1);
  bfly8_inv(v);

  float* y1 = y + ((size_t)bp * NH + h) * LEN;
  float* y2 = y + ((size_t)(bp + 8) * NH + h) * LEN;
  const float sc = 1.0f / (float)LEN;
#pragma unroll
  for (int p = 0; p < 8; ++p) {
    y1[t + 512 * p] = v[p].x * sc;
    y2[t + 512 * p] = v[p].y * sc;
  }
}

extern "C" void kernel_launch(void* const* d_in, const int* in_sizes, int n_in,
                              void* d_out, int out_size, void* d_ws, size_t ws_size,
                              hipStream_t stream) {
  const float* u    = (const float*)d_in[0];
  const float* Lre  = (const float*)d_in[1];
  const float* Lim  = (const float*)d_in[2];
  const float* Pre  = (const float*)d_in[3];
  const float* Pim  = (const float*)d_in[4];
  const float* Bre  = (const float*)d_in[5];
  const float* Bim  = (const float*)d_in[6];
  const float* Cre  = (const float*)d_in[7];
  const float* Cim  = (const float*)d_in[8];
  const float* lstep = (const float*)d_in[9];
  float* y = (float*)d_out;

  s4_prep<<<(NH * NSTATE + 255) / 256, 256, 0, stream>>>(Lre, Lim, Pre, Pim, Bre, Bim, Cre, Cim);
  s4_kernel_freq<<<NH * 4, 256, 0, stream>>>(lstep);
  s4_fftconv<<<NH * (NB / 2), 512, 0, stream>>>(u, y);
}

// Round 2
// 180.296 us; speedup vs baseline: 1.0399x; 1.0006x over previous
//
#include <hip/hip_runtime.h>
#include <math.h>

#define NSTATE 64
#define LEN    4096
#define NH     256
#define NB     16

// K in base-8 digit-reversed order (fftconv consumption order).
// Position p holds natural frequency rev8_12(p) (rev8_12 is an involution).
__device__ float2 g_ksym[NH * LEN];

__device__ __forceinline__ int rev8_12(int p) {
  return ((p & 7) << 9) | (((p >> 3) & 7) << 6) | (((p >> 6) & 7) << 3) | (p >> 9);
}

// ---------------- complex helpers ----------------
__device__ __forceinline__ float2 cadd(float2 a, float2 b){ return make_float2(a.x+b.x, a.y+b.y); }
__device__ __forceinline__ float2 csub(float2 a, float2 b){ return make_float2(a.x-b.x, a.y-b.y); }
__device__ __forceinline__ float2 cmul(float2 a, float2 b){ return make_float2(a.x*b.x - a.y*b.y, a.x*b.y + a.y*b.x); }
__device__ __forceinline__ float2 mulnegi(float2 a){ return make_float2(a.y, -a.x); }
__device__ __forceinline__ float2 mulposi(float2 a){ return make_float2(-a.y, a.x); }

#define RSQ2 0.70710678118654752f

__device__ __forceinline__ void bfly8_fwd(float2 v[8]) {
  float2 a0 = cadd(v[0], v[4]), b0 = csub(v[0], v[4]);
  float2 a1 = cadd(v[1], v[5]), d1 = csub(v[1], v[5]);
  float2 a2 = cadd(v[2], v[6]), d2 = csub(v[2], v[6]);
  float2 a3 = cadd(v[3], v[7]), d3 = csub(v[3], v[7]);
  float2 b1 = make_float2(RSQ2 * (d1.x + d1.y), RSQ2 * (d1.y - d1.x));
  float2 b2 = mulnegi(d2);
  float2 b3 = make_float2(RSQ2 * (d3.y - d3.x), -RSQ2 * (d3.x + d3.y));
  float2 u0 = cadd(a0, a2), u1 = csub(a0, a2), u2 = cadd(a1, a3), u3 = csub(a1, a3);
  v[0] = cadd(u0, u2);
  v[2] = cadd(u1, mulnegi(u3));
  v[4] = csub(u0, u2);
  v[6] = cadd(u1, mulposi(u3));
  float2 w0 = cadd(b0, b2), w1 = csub(b0, b2), w2 = cadd(b1, b3), w3 = csub(b1, b3);
  v[1] = cadd(w0, w2);
  v[3] = cadd(w1, mulnegi(w3));
  v[5] = csub(w0, w2);
  v[7] = cadd(w1, mulposi(w3));
}

__device__ __forceinline__ void bfly8_inv(float2 v[8]) {
  float2 a0 = cadd(v[0], v[4]), b0 = csub(v[0], v[4]);
  float2 a1 = cadd(v[1], v[5]), d1 = csub(v[1], v[5]);
  float2 a2 = cadd(v[2], v[6]), d2 = csub(v[2], v[6]);
  float2 a3 = cadd(v[3], v[7]), d3 = csub(v[3], v[7]);
  float2 b1 = make_float2(RSQ2 * (d1.x - d1.y), RSQ2 * (d1.x + d1.y));
  float2 b2 = mulposi(d2);
  float2 b3 = make_float2(-RSQ2 * (d3.x + d3.y), RSQ2 * (d3.x - d3.y));
  float2 u0 = cadd(a0, a2), u1 = csub(a0, a2), u2 = cadd(a1, a3), u3 = csub(a1, a3);
  v[0] = cadd(u0, u2);
  v[2] = cadd(u1, mulposi(u3));
  v[4] = csub(u0, u2);
  v[6] = cadd(u1, mulnegi(u3));
  float2 w0 = cadd(b0, b2), w1 = csub(b0, b2), w2 = cadd(b1, b3), w3 = csub(b1, b3);
  v[1] = cadd(w0, w2);
  v[3] = cadd(w1, mulposi(w3));
  v[5] = csub(w0, w2);
  v[7] = cadd(w1, mulnegi(w3));
}

__device__ __forceinline__ void twiddle7(float2 v[8], float wr, float wi) {
  float2 w1 = make_float2(wr, wi);
  float2 w2 = cmul(w1, w1);
  float2 w3 = cmul(w2, w1);
  float2 w4 = cmul(w2, w2);
  float2 w5 = cmul(w3, w2);
  float2 w6 = cmul(w3, w3);
  float2 w7 = cmul(w4, w3);
  v[1] = cmul(v[1], w1); v[2] = cmul(v[2], w2); v[3] = cmul(v[3], w3);
  v[4] = cmul(v[4], w4); v[5] = cmul(v[5], w5); v[6] = cmul(v[6], w6);
  v[7] = cmul(v[7], w7);
}

// wave-local LDS fence: all our ds_writes complete before subsequent ds_reads issue.
#define WAVE_SYNC() asm volatile("s_waitcnt lgkmcnt(0)" ::: "memory")

// ---------------- frequency-domain S4 kernel (prep fused, LDS params) ----------------
// Grid NH*8 blocks x 256 threads. Thread (h, j) with j in [0,2048) evaluates K at
// TWO points: A: l=j, and B: the conjugate mirror (4096-j)&4095 (g,c = conj of A's).
// j==0 -> B is l=2048 (self-paired), computed directly.
// Threads 0..63 first compute the per-(h,n) Cauchy params into LDS:
//   sA={lam_r,lam_i,|P|^2,pad} sB={v0r,v0i,v1r,v1i} sC={v2r,v2i}
// Symmetrized K written DIRECTLY to the base-8 digit-reversed positions.
__global__ __launch_bounds__(256) void s4_kernel_freq(
    const float* __restrict__ Lre, const float* __restrict__ Lim,
    const float* __restrict__ Pre, const float* __restrict__ Pim,
    const float* __restrict__ Bre, const float* __restrict__ Bim,
    const float* __restrict__ Cre, const float* __restrict__ Cim,
    const float* __restrict__ log_step)
{
  __shared__ float4 sA[NSTATE];
  __shared__ float4 sB[NSTATE];
  __shared__ float2 sC[NSTATE];

  const int blk = blockIdx.x;
  const int h = blk >> 3;
  const int j = ((blk & 7) << 8) | threadIdx.x;  // 0..2047

  if (threadIdx.x < NSTATE) {
    int idx = h * NSTATE + threadIdx.x;
    float lr = Lre[idx], li = Lim[idx];
    float pr = Pre[idx], pi = Pim[idx];
    float br = Bre[idx], bi = Bim[idx];
    float cr = Cre[idx], ci = Cim[idx];
    sA[threadIdx.x] = make_float4(lr, li, pr * pr + pi * pi, 0.0f);
    sB[threadIdx.x] = make_float4(cr * br + ci * bi, cr * bi - ci * br,
                                  cr * pr + ci * pi, cr * pi - ci * pr);
    sC[threadIdx.x] = make_float2(pr * br + pi * bi, pr * bi - pi * br);
  }

  const float step = expf(log_step[h]);
  const float ts = 2.0f / step;
  const float NEG2PI = -6.2831853071795864769f;

  float gar, gai, car, cai, gbr, gbi, cbr, cbi;
  {
    float so, co;
    sincosf(NEG2PI * ((float)j * (1.0f / (float)LEN)), &so, &co);
    float dr = 1.0f + co, di = so;
    float inv = 1.0f / fmaf(dr, dr, di * di);
    car = 2.0f * dr * inv; cai = -2.0f * di * inv;
    float nr = 1.0f - co, ni = -so;
    gar = ts * (fmaf(nr, dr, ni * di) * inv);
    gai = ts * (fmaf(ni, dr, -nr * di) * inv);
  }
  if (j == 0) {           // point B is l = 2048 (self-paired), compute directly
    float so, co;
    sincosf(NEG2PI * 0.5f, &so, &co);
    float dr = 1.0f + co, di = so;
    float inv = 1.0f / fmaf(dr, dr, di * di);
    cbr = 2.0f * dr * inv; cbi = -2.0f * di * inv;
    float nr = 1.0f - co, ni = -so;
    gbr = ts * (fmaf(nr, dr, ni * di) * inv);
    gbi = ts * (fmaf(ni, dr, -nr * di) * inv);
  } else {                // B = mirror of A: Omega -> conj => g,c -> conj
    gbr = gar; gbi = -gai; cbr = car; cbi = -cai;
  }

  float A00r=0,A00i=0,A01r=0,A01i=0,A10r=0,A10i=0,A11r=0,A11i=0;
  float B00r=0,B00i=0,B01r=0,B01i=0,B10r=0,B10i=0,B11r=0,B11i=0;

  __syncthreads();

#define CAUCHY(gre, gim, k00r,k00i,k01r,k01i,k10r,k10i,k11r,k11i)            \
  {                                                                          \
    float rd = gre - Av.x, id = gim - Av.y;                                  \
    float idn = __builtin_amdgcn_rcpf(fmaf(rd, rd, id * id));                \
    float ir = rd * idn, ii = -(id * idn);                                   \
    k00r = fmaf(Bv.x, ir, k00r); k00r = fmaf(-Bv.y, ii, k00r);               \
    k00i = fmaf(Bv.x, ii, k00i); k00i = fmaf(Bv.y, ir, k00i);                \
    k01r = fmaf(Bv.z, ir, k01r); k01r = fmaf(-Bv.w, ii, k01r);               \
    k01i = fmaf(Bv.z, ii, k01i); k01i = fmaf(Bv.w, ir, k01i);                \
    k10r = fmaf(Cv.x, ir, k10r); k10r = fmaf(-Cv.y, ii, k10r);               \
    k10i = fmaf(Cv.x, ii, k10i); k10i = fmaf(Cv.y, ir, k10i);                \
    k11r = fmaf(Av.z, ir, k11r); k11i = fmaf(Av.z, ii, k11i);                \
  }

#pragma unroll 8
  for (int n = 0; n < NSTATE; ++n) {
    float4 Av = sA[n];
    float4 Bv = sB[n];
    float2 Cv = sC[n];
    CAUCHY(gar, gai, A00r,A00i,A01r,A01i,A10r,A10i,A11r,A11i)
    CAUCHY(gbr, gbi, B00r,B00i,B01r,B01i,B10r,B10i,B11r,B11i)
  }
#undef CAUCHY

#define FINISH(cr_, ci_, k00r,k00i,k01r,k01i,k10r,k10i,k11r,k11i, Kr, Ki)    \
  {                                                                          \
    float rr = 1.0f + k11r, ri = k11i;                                       \
    float rinv = 1.0f / fmaf(rr, rr, ri * ri);                               \
    float pr_ = k01r * k10r - k01i * k10i;                                   \
    float pi_ = k01r * k10i + k01i * k10r;                                   \
    float wr = (pr_ * rr + pi_ * ri) * rinv;                                 \
    float wi = (pi_ * rr - pr_ * ri) * rinv;                                 \
    float sr = k00r - wr, si = k00i - wi;                                    \
    Kr = cr_ * sr - ci_ * si; Ki = cr_ * si + ci_ * sr;                      \
  }

  float Kar, Kai, Kbr, Kbi;
  FINISH(car, cai, A00r,A00i,A01r,A01i,A10r,A10i,A11r,A11i, Kar, Kai)
  FINISH(cbr, cbi, B00r,B00i,B01r,B01i,B10r,B10i,B11r,B11i, Kbr, Kbi)
#undef FINISH

  float2* out = g_ksym + (size_t)h * LEN;
  if (j == 0) {
    out[rev8_12(0)]    = make_float2(Kar, 0.0f);   // Ksym[0]    = Re K[0]
    out[rev8_12(2048)] = make_float2(Kbr, 0.0f);   // Ksym[2048] = Re K[2048]
  } else {
    float fr = 0.5f * (Kar + Kbr), fi = 0.5f * (Kai - Kbi);
    out[rev8_12(j)]       = make_float2(fr, fi);
    out[rev8_12(LEN - j)] = make_float2(fr, -fi);  // conj pair
  }
}

// ---------------- FFT convolution: register radix-8, 4096 = 8^4 ----------------
// Wave-local schedule: after the block-wide stride-512 stage, each of the 8 waves
// owns one independent 512-point sub-FFT in a private 576-float2 LDS region.
// Only TWO block barriers; interior stage handoffs are wave-local lgkmcnt fences.
__global__ __launch_bounds__(512) void s4_fftconv(const float* __restrict__ u,
                                                 float* __restrict__ y)
{
  __shared__ float2 X[4608];   // 8 waves x 576

  const int t = threadIdx.x;
  const int bid = blockIdx.x;
  const int h  = bid & (NH - 1);
  const int bp = bid >> 8;

  const int w  = t >> 6;        // wave id == radix-8 stage-1 output digit r1
  const int i  = t & 63;        // lane within wave
  const int i3 = i >> 3;
  const int i7 = i & 7;
  const int R  = 576 * w;       // private LDS region base

  float c1, s1, c2, s2, c3, s3;
  sincosf((float)t  * (-6.2831853071795864769f / 4096.0f), &s1, &c1);
  sincosf((float)i  * (-6.2831853071795864769f /  512.0f), &s2, &c2);
  sincosf((float)i7 * (-6.2831853071795864769f /   64.0f), &s3, &c3);

  const float* u1 = u + ((size_t)bp * NH + h) * LEN;
  const float* u2 = u + ((size_t)(bp + 8) * NH + h) * LEN;

  float2 v[8];
#pragma unroll
  for (int m = 0; m < 8; ++m)
    v[m] = make_float2(u1[t + 512 * m], u2[t + 512 * m]);
  bfly8_fwd(v);
  twiddle7(v, c1, s1);
#pragma unroll
  for (int m = 0; m < 8; ++m) X[576 * m + t] = v[m];   // scatter: group m region
  __syncthreads();                                     // block barrier #1

  // ---- stage 2 (stride 64 within group), wave-local from here ----
#pragma unroll
  for (int m = 0; m < 8; ++m) v[m] = X[R + i + 64 * m];
  bfly8_fwd(v);
  twiddle7(v, c2, s2);
#pragma unroll
  for (int m = 0; m < 8; ++m) X[R + 68 * m + i] = v[m];
  WAVE_SYNC();

  // ---- stage 3 (stride 8) ----
#pragma unroll
  for (int m = 0; m < 8; ++m) v[m] = X[R + 68 * i3 + i7 + 8 * m];
  bfly8_fwd(v);
  twiddle7(v, c3, s3);
#pragma unroll
  for (int m = 0; m < 8; ++m) X[R + 9 * (8 * i3 + m) + i7] = v[m];
  WAVE_SYNC();

  // ---- stage 4 fwd + pointwise + stage 4 inv (registers) ----
  {
    const float4* kp = (const float4*)(g_ksym + (size_t)h * LEN + 8 * t);
    float4 k0 = kp[0], k1 = kp[1], k2 = kp[2], k3 = kp[3];
#pragma unroll
    for (int m = 0; m < 8; ++m) v[m] = X[R + 9 * i + m];
    bfly8_fwd(v);
    v[0] = cmul(v[0], make_float2(k0.x, k0.y));
    v[1] = cmul(v[1], make_float2(k0.z, k0.w));
    v[2] = cmul(v[2], make_float2(k1.x, k1.y));
    v[3] = cmul(v[3], make_float2(k1.z, k1.w));
    v[4] = cmul(v[4], make_float2(k2.x, k2.y));
    v[5] = cmul(v[5], make_float2(k2.z, k2.w));
    v[6] = cmul(v[6], make_float2(k3.x, k3.y));
    v[7] = cmul(v[7], make_float2(k3.z, k3.w));
    bfly8_inv(v);
#pragma unroll
    for (int p = 0; p < 8; ++p) X[R + 9 * i + p] = v[p];
  }
  WAVE_SYNC();

  // ---- stage 3 inverse ----
#pragma unroll
  for (int m = 0; m < 8; ++m) v[m] = X[R + 9 * (8 * i3 + m) + i7];
  twiddle7(v, c3, -s3);
  bfly8_inv(v);
#pragma unroll
  for (int p = 0; p < 8; ++p) X[R + 68 * i3 + i7 + 8 * p] = v[p];
  WAVE_SYNC();

  // ---- stage 2 inverse ----
#pragma unroll
  for (int m = 0; m < 8; ++m) v[m] = X[R + 68 * m + i];
  twiddle7(v, c2, -s2);
  bfly8_inv(v);
#pragma unroll
  for (int p = 0; p < 8; ++p) X[R + i + 64 * p] = v[p];
  __syncthreads();                                     // block barrier #2

  // ---- stage 1 inverse (block-wide gather) ----
#pragma unroll
  for (int m = 0; m < 8; ++m) v[m] = X[576 * m + t];
  twiddle7(v, c1, -s1);
  bfly8_inv(v);

  float* y1 = y + ((size_t)bp * NH + h) * LEN;
  float* y2 = y + ((size_t)(bp + 8) * NH + h) * LEN;
  const float sc = 1.0f / (float)LEN;
#pragma unroll
  for (int p = 0; p < 8; ++p) {
    y1[t + 512 * p] = v[p].x * sc;
    y2[t + 512 * p] = v[p].y * sc;
  }
}

extern "C" void kernel_launch(void* const* d_in, const int* in_sizes, int n_in,
                              void* d_out, int out_size, void* d_ws, size_t ws_size,
                              hipStream_t stream) {
  const float* u    = (const float*)d_in[0];
  const float* Lre  = (const float*)d_in[1];
  const float* Lim  = (const float*)d_in[2];
  const float* Pre  = (const float*)d_in[3];
  const float* Pim  = (const float*)d_in[4];
  const float* Bre  = (const float*)d_in[5];
  const float* Bim  = (const float*)d_in[6];
  const float* Cre  = (const float*)d_in[7];
  const float* Cim  = (const float*)d_in[8];
  const float* lstep = (const float*)d_in[9];
  float* y = (float*)d_out;

  s4_kernel_freq<<<NH * 8, 256, 0, stream>>>(Lre, Lim, Pre, Pim, Bre, Bim, Cre, Cim, lstep);
  s4_fftconv<<<NH * (NB / 2), 512, 0, stream>>>(u, y);
}

// Round 3
// 175.398 us; speedup vs baseline: 1.0690x; 1.0279x over previous
//
#include <hip/hip_runtime.h>
#include <math.h>

#define NSTATE 64
#define LEN    4096
#define NH     256
#define NB     16

typedef float f2 __attribute__((ext_vector_type(2)));

// K in base-8 digit-reversed order (fftconv consumption order).
// Position p holds natural frequency rev8_12(p) (rev8_12 is an involution).
__device__ f2 g_ksym[NH * LEN];

__device__ __forceinline__ int rev8_12(int p) {
  return ((p & 7) << 9) | (((p >> 3) & 7) << 6) | (((p >> 6) & 7) << 3) | (p >> 9);
}

__device__ __forceinline__ f2 mkf2(float a, float b){ f2 r; r.x = a; r.y = b; return r; }

// ---------------- packed-f32 complex primitives (VOP3P) ----------------
// r = a*b : r.x = a.y*(-b.y) + a.x*b.x ; r.y = a.y*b.x + a.x*b.y
__device__ __forceinline__ f2 cmul_pk(f2 a, f2 b) {
  f2 t, r;
  asm("v_pk_mul_f32 %0, %1, %2 op_sel:[0,0] op_sel_hi:[0,1]"
      : "=v"(t) : "v"(a), "v"(b));
  asm("v_pk_fma_f32 %0, %1, %2, %3 op_sel:[1,1,0] op_sel_hi:[1,0,1] neg_lo:[0,1,0]"
      : "=v"(r) : "v"(a), "v"(b), "v"(t));
  return r;
}
// r = a*conj(b) : r.x = a.x*b.x + a.y*b.y ; r.y = a.y*b.x - a.x*b.y
__device__ __forceinline__ f2 cmulc_pk(f2 a, f2 b) {
  f2 t, r;
  asm("v_pk_mul_f32 %0, %1, %2 op_sel:[0,0] op_sel_hi:[0,1] neg_hi:[0,1]"
      : "=v"(t) : "v"(a), "v"(b));
  asm("v_pk_fma_f32 %0, %1, %2, %3 op_sel:[1,1,0] op_sel_hi:[1,0,1]"
      : "=v"(r) : "v"(a), "v"(b), "v"(t));
  return r;
}
// acc += v*e (complex MAC; same fma ordering as the old scalar code)
__device__ __forceinline__ void cmac_pk(f2& acc, f2 v, f2 e) {
  asm("v_pk_fma_f32 %0, %1, %2, %0 op_sel:[0,0,0] op_sel_hi:[0,1,1]"
      : "+v"(acc) : "v"(v), "v"(e));
  asm("v_pk_fma_f32 %0, %1, %2, %0 op_sel:[1,1,0] op_sel_hi:[1,0,1] neg_lo:[0,1,0]"
      : "+v"(acc) : "v"(v), "v"(e));
}
// acc += a .* b  (elementwise packed fma)
__device__ __forceinline__ void pk_fma(f2& acc, f2 a, f2 b) {
  asm("v_pk_fma_f32 %0, %1, %2, %0" : "+v"(acc) : "v"(a), "v"(b));
}

#define RSQ2 0.70710678118654752f

// ---------------- radix-8 butterflies (vector adds pack to v_pk_add_f32) ----
__device__ __forceinline__ void bfly8_fwd(f2 v[8]) {
  f2 a0 = v[0] + v[4], b0 = v[0] - v[4];
  f2 a1 = v[1] + v[5], d1 = v[1] - v[5];
  f2 a2 = v[2] + v[6], d2 = v[2] - v[6];
  f2 a3 = v[3] + v[7], d3 = v[3] - v[7];
  f2 b1 = mkf2(RSQ2 * (d1.x + d1.y), RSQ2 * (d1.y - d1.x));
  f2 b3 = mkf2(RSQ2 * (d3.y - d3.x), -RSQ2 * (d3.x + d3.y));
  f2 u0 = a0 + a2, u1 = a0 - a2, u2 = a1 + a3, u3 = a1 - a3;
  v[0] = u0 + u2;
  v[2] = mkf2(u1.x + u3.y, u1.y - u3.x);
  v[4] = u0 - u2;
  v[6] = mkf2(u1.x - u3.y, u1.y + u3.x);
  f2 w0 = mkf2(b0.x + d2.y, b0.y - d2.x);
  f2 w1 = mkf2(b0.x - d2.y, b0.y + d2.x);
  f2 w2 = b1 + b3, w3 = b1 - b3;
  v[1] = w0 + w2;
  v[3] = mkf2(w1.x + w3.y, w1.y - w3.x);
  v[5] = w0 - w2;
  v[7] = mkf2(w1.x - w3.y, w1.y + w3.x);
}

__device__ __forceinline__ void bfly8_inv(f2 v[8]) {
  f2 a0 = v[0] + v[4], b0 = v[0] - v[4];
  f2 a1 = v[1] + v[5], d1 = v[1] - v[5];
  f2 a2 = v[2] + v[6], d2 = v[2] - v[6];
  f2 a3 = v[3] + v[7], d3 = v[3] - v[7];
  f2 b1 = mkf2(RSQ2 * (d1.x - d1.y), RSQ2 * (d1.x + d1.y));
  f2 b3 = mkf2(-RSQ2 * (d3.x + d3.y), RSQ2 * (d3.x - d3.y));
  f2 u0 = a0 + a2, u1 = a0 - a2, u2 = a1 + a3, u3 = a1 - a3;
  v[0] = u0 + u2;
  v[2] = mkf2(u1.x - u3.y, u1.y + u3.x);
  v[4] = u0 - u2;
  v[6] = mkf2(u1.x + u3.y, u1.y - u3.x);
  f2 w0 = mkf2(b0.x - d2.y, b0.y + d2.x);
  f2 w1 = mkf2(b0.x + d2.y, b0.y - d2.x);
  f2 w2 = b1 + b3, w3 = b1 - b3;
  v[1] = w0 + w2;
  v[3] = mkf2(w1.x - w3.y, w1.y + w3.x);
  v[5] = w0 - w2;
  v[7] = mkf2(w1.x + w3.y, w1.y - w3.x);
}

// forward twiddle: v[m] *= w1^m   (powers rebuilt per call: keeps VGPR <= 64)
__device__ __forceinline__ void twiddle7(f2 v[8], f2 w1) {
  f2 w2 = cmul_pk(w1, w1);
  f2 w3 = cmul_pk(w2, w1);
  f2 w4 = cmul_pk(w2, w2);
  f2 w5 = cmul_pk(w3, w2);
  f2 w6 = cmul_pk(w3, w3);
  f2 w7 = cmul_pk(w4, w3);
  v[1] = cmul_pk(v[1], w1); v[2] = cmul_pk(v[2], w2); v[3] = cmul_pk(v[3], w3);
  v[4] = cmul_pk(v[4], w4); v[5] = cmul_pk(v[5], w5); v[6] = cmul_pk(v[6], w6);
  v[7] = cmul_pk(v[7], w7);
}
// inverse twiddle: v[m] *= conj(w1^m)
__device__ __forceinline__ void twiddle7c(f2 v[8], f2 w1) {
  f2 w2 = cmul_pk(w1, w1);
  f2 w3 = cmul_pk(w2, w1);
  f2 w4 = cmul_pk(w2, w2);
  f2 w5 = cmul_pk(w3, w2);
  f2 w6 = cmul_pk(w3, w3);
  f2 w7 = cmul_pk(w4, w3);
  v[1] = cmulc_pk(v[1], w1); v[2] = cmulc_pk(v[2], w2); v[3] = cmulc_pk(v[3], w3);
  v[4] = cmulc_pk(v[4], w4); v[5] = cmulc_pk(v[5], w5); v[6] = cmulc_pk(v[6], w6);
  v[7] = cmulc_pk(v[7], w7);
}

// wave-local LDS fence
#define WAVE_SYNC() asm volatile("s_waitcnt lgkmcnt(0)" ::: "memory")

// ---------------- frequency-domain S4 kernel (prep fused, packed CAUCHY) ----
// Grid NH*8 x 256. Thread (h,j), j in [0,2048): points A: l=j and B: conj mirror.
// LDS params per (h,n): sLam={lam_r,lam_i,|P|2,|P|2} sV01={v0r,v0i,v1r,v1i} sV2={v2r,v2i}
__global__ __launch_bounds__(256) void s4_kernel_freq(
    const float* __restrict__ Lre, const float* __restrict__ Lim,
    const float* __restrict__ Pre, const float* __restrict__ Pim,
    const float* __restrict__ Bre, const float* __restrict__ Bim,
    const float* __restrict__ Cre, const float* __restrict__ Cim,
    const float* __restrict__ log_step)
{
  __shared__ float4 sLam[NSTATE];
  __shared__ float4 sV01[NSTATE];
  __shared__ f2     sV2[NSTATE];

  const int blk = blockIdx.x;
  const int h = blk >> 3;
  const int j = ((blk & 7) << 8) | threadIdx.x;  // 0..2047

  if (threadIdx.x < NSTATE) {
    int idx = h * NSTATE + threadIdx.x;
    float lr = Lre[idx], li = Lim[idx];
    float pr = Pre[idx], pi = Pim[idx];
    float br = Bre[idx], bi = Bim[idx];
    float cr = Cre[idx], ci = Cim[idx];
    float pp = pr * pr + pi * pi;
    sLam[threadIdx.x] = make_float4(lr, li, pp, pp);
    sV01[threadIdx.x] = make_float4(cr * br + ci * bi, cr * bi - ci * br,
                                    cr * pr + ci * pi, cr * pi - ci * pr);
    sV2[threadIdx.x] = mkf2(pr * br + pi * bi, pr * bi - pi * br);
  }

  const float step = expf(log_step[h]);
  const float ts = 2.0f / step;
  const float NEG2PI = -6.2831853071795864769f;

  float gar, gai, car, cai, gbr, gbi, cbr, cbi;
  {
    float so, co;
    sincosf(NEG2PI * ((float)j * (1.0f / (float)LEN)), &so, &co);
    float dr = 1.0f + co, di = so;
    float inv = 1.0f / fmaf(dr, dr, di * di);
    car = 2.0f * dr * inv; cai = -2.0f * di * inv;
    float nr = 1.0f - co, ni = -so;
    gar = ts * (fmaf(nr, dr, ni * di) * inv);
    gai = ts * (fmaf(ni, dr, -nr * di) * inv);
  }
  if (j == 0) {           // point B is l = 2048 (self-paired), compute directly
    float so, co;
    sincosf(NEG2PI * 0.5f, &so, &co);
    float dr = 1.0f + co, di = so;
    float inv = 1.0f / fmaf(dr, dr, di * di);
    cbr = 2.0f * dr * inv; cbi = -2.0f * di * inv;
    float nr = 1.0f - co, ni = -so;
    gbr = ts * (fmaf(nr, dr, ni * di) * inv);
    gbi = ts * (fmaf(ni, dr, -nr * di) * inv);
  } else {                // B = mirror of A: Omega -> conj => g,c -> conj
    gbr = gar; gbi = -gai; cbr = car; cbi = -cai;
  }
  const f2 gA = mkf2(gar, gai);
  const f2 gB = mkf2(gbr, gbi);

  f2 A00 = {0,0}, A01 = {0,0}, A10 = {0,0}, A11 = {0,0};
  f2 B00 = {0,0}, B01 = {0,0}, B10 = {0,0}, B11 = {0,0};

  __syncthreads();

#pragma unroll 8
  for (int n = 0; n < NSTATE; ++n) {
    float4 L4 = sLam[n];
    float4 V4 = sV01[n];
    f2 v2 = sV2[n];
    f2 lam = mkf2(L4.x, L4.y);
    f2 pp  = mkf2(L4.z, L4.w);
    f2 v0  = mkf2(V4.x, V4.y);
    f2 v1  = mkf2(V4.z, V4.w);
    {
      f2 d = gA - lam;
      float idn = __builtin_amdgcn_rcpf(fmaf(d.x, d.x, d.y * d.y));
      f2 e = mkf2(d.x * idn, -(d.y * idn));
      cmac_pk(A00, v0, e); cmac_pk(A01, v1, e);
      cmac_pk(A10, v2, e); pk_fma(A11, pp, e);
    }
    {
      f2 d = gB - lam;
      float idn = __builtin_amdgcn_rcpf(fmaf(d.x, d.x, d.y * d.y));
      f2 e = mkf2(d.x * idn, -(d.y * idn));
      cmac_pk(B00, v0, e); cmac_pk(B01, v1, e);
      cmac_pk(B10, v2, e); pk_fma(B11, pp, e);
    }
  }

#define FINISH(cr_, ci_, k00,k01,k10,k11, Kr, Ki)                            \
  {                                                                          \
    float rr = 1.0f + k11.x, ri = k11.y;                                     \
    float rinv = 1.0f / fmaf(rr, rr, ri * ri);                               \
    float pr_ = k01.x * k10.x - k01.y * k10.y;                               \
    float pi_ = k01.x * k10.y + k01.y * k10.x;                               \
    float wr = (pr_ * rr + pi_ * ri) * rinv;                                 \
    float wi = (pi_ * rr - pr_ * ri) * rinv;                                 \
    float sr = k00.x - wr, si = k00.y - wi;                                  \
    Kr = cr_ * sr - ci_ * si; Ki = cr_ * si + ci_ * sr;                      \
  }

  float Kar, Kai, Kbr, Kbi;
  FINISH(car, cai, A00, A01, A10, A11, Kar, Kai)
  FINISH(cbr, cbi, B00, B01, B10, B11, Kbr, Kbi)
#undef FINISH

  f2* out = g_ksym + (size_t)h * LEN;
  if (j == 0) {
    out[rev8_12(0)]    = mkf2(Kar, 0.0f);   // Ksym[0]    = Re K[0]
    out[rev8_12(2048)] = mkf2(Kbr, 0.0f);   // Ksym[2048] = Re K[2048]
  } else {
    float fr = 0.5f * (Kar + Kbr), fi = 0.5f * (Kai - Kbi);
    out[rev8_12(j)]       = mkf2(fr, fi);
    out[rev8_12(LEN - j)] = mkf2(fr, -fi);  // conj pair
  }
}

// ---------------- FFT convolution: register radix-8, 4096 = 8^4 ----------------
// Wave-local schedule: after the block-wide stride-512 stage, each of the 8 waves
// owns one independent 512-point sub-FFT in a private 576-f2 LDS region.
// Only TWO block barriers; interior stage handoffs are wave-local lgkmcnt fences.
__global__ __launch_bounds__(512) void s4_fftconv(const float* __restrict__ u,
                                                 float* __restrict__ y)
{
  __shared__ f2 X[4608];   // 8 waves x 576

  const int t = threadIdx.x;
  const int bid = blockIdx.x;
  const int h  = bid & (NH - 1);
  const int bp = bid >> 8;

  const int w  = t >> 6;        // wave id == radix-8 stage-1 output digit r1
  const int i  = t & 63;        // lane within wave
  const int i3 = i >> 3;
  const int i7 = i & 7;
  const int R  = 576 * w;       // private LDS region base

  float c1, s1, c2, s2, c3, s3;
  sincosf((float)t  * (-6.2831853071795864769f / 4096.0f), &s1, &c1);
  sincosf((float)i  * (-6.2831853071795864769f /  512.0f), &s2, &c2);
  sincosf((float)i7 * (-6.2831853071795864769f /   64.0f), &s3, &c3);
  const f2 W1 = mkf2(c1, s1), W2 = mkf2(c2, s2), W3 = mkf2(c3, s3);

  const float* u1 = u + ((size_t)bp * NH + h) * LEN;
  const float* u2 = u + ((size_t)(bp + 8) * NH + h) * LEN;

  f2 v[8];
#pragma unroll
  for (int m = 0; m < 8; ++m)
    v[m] = mkf2(u1[t + 512 * m], u2[t + 512 * m]);
  bfly8_fwd(v);
  twiddle7(v, W1);
#pragma unroll
  for (int m = 0; m < 8; ++m) X[576 * m + t] = v[m];   // scatter: group m region
  __syncthreads();                                     // block barrier #1

  // ---- stage 2 (stride 64 within group), wave-local from here ----
#pragma unroll
  for (int m = 0; m < 8; ++m) v[m] = X[R + i + 64 * m];
  bfly8_fwd(v);
  twiddle7(v, W2);
#pragma unroll
  for (int m = 0; m < 8; ++m) X[R + 68 * m + i] = v[m];
  WAVE_SYNC();

  // ---- stage 3 (stride 8) ----
#pragma unroll
  for (int m = 0; m < 8; ++m) v[m] = X[R + 68 * i3 + i7 + 8 * m];
  bfly8_fwd(v);
  twiddle7(v, W3);
#pragma unroll
  for (int m = 0; m < 8; ++m) X[R + 9 * (8 * i3 + m) + i7] = v[m];
  WAVE_SYNC();

  // ---- stage 4 fwd + pointwise + stage 4 inv (registers) ----
  {
    const float4* kp = (const float4*)(g_ksym + (size_t)h * LEN + 8 * t);
    float4 k0 = kp[0], k1 = kp[1], k2 = kp[2], k3 = kp[3];
#pragma unroll
    for (int m = 0; m < 8; ++m) v[m] = X[R + 9 * i + m];
    bfly8_fwd(v);
    v[0] = cmul_pk(v[0], mkf2(k0.x, k0.y));
    v[1] = cmul_pk(v[1], mkf2(k0.z, k0.w));
    v[2] = cmul_pk(v[2], mkf2(k1.x, k1.y));
    v[3] = cmul_pk(v[3], mkf2(k1.z, k1.w));
    v[4] = cmul_pk(v[4], mkf2(k2.x, k2.y));
    v[5] = cmul_pk(v[5], mkf2(k2.z, k2.w));
    v[6] = cmul_pk(v[6], mkf2(k3.x, k3.y));
    v[7] = cmul_pk(v[7], mkf2(k3.z, k3.w));
    bfly8_inv(v);
#pragma unroll
    for (int p = 0; p < 8; ++p) X[R + 9 * i + p] = v[p];
  }
  WAVE_SYNC();

  // ---- stage 3 inverse ----
#pragma unroll
  for (int m = 0; m < 8; ++m) v[m] = X[R + 9 * (8 * i3 + m) + i7];
  twiddle7c(v, W3);
  bfly8_inv(v);
#pragma unroll
  for (int p = 0; p < 8; ++p) X[R + 68 * i3 + i7 + 8 * p] = v[p];
  WAVE_SYNC();

  // ---- stage 2 inverse ----
#pragma unroll
  for (int m = 0; m < 8; ++m) v[m] = X[R + 68 * m + i];
  twiddle7c(v, W2);
  bfly8_inv(v);
#pragma unroll
  for (int p = 0; p < 8; ++p) X[R + i + 64 * p] = v[p];
  __syncthreads();                                     // block barrier #2

  // ---- stage 1 inverse (block-wide gather) ----
#pragma unroll
  for (int m = 0; m < 8; ++m) v[m] = X[576 * m + t];
  twiddle7c(v, W1);
  bfly8_inv(v);

  float* y1 = y + ((size_t)bp * NH + h) * LEN;
  float* y2 = y + ((size_t)(bp + 8) * NH + h) * LEN;
  const float sc = 1.0f / (float)LEN;
#pragma unroll
  for (int p = 0; p < 8; ++p) {
    y1[t + 512 * p] = v[p].x * sc;
    y2[t + 512 * p] = v[p].y * sc;
  }
}

extern "C" void kernel_launch(void* const* d_in, const int* in_sizes, int n_in,
                              void* d_out, int out_size, void* d_ws, size_t ws_size,
                              hipStream_t stream) {
  const float* u    = (const float*)d_in[0];
  const float* Lre  = (const float*)d_in[1];
  const float* Lim  = (const float*)d_in[2];
  const float* Pre  = (const float*)d_in[3];
  const float* Pim  = (const float*)d_in[4];
  const float* Bre  = (const float*)d_in[5];
  const float* Bim  = (const float*)d_in[6];
  const float* Cre  = (const float*)d_in[7];
  const float* Cim  = (const float*)d_in[8];
  const float* lstep = (const float*)d_in[9];
  float* y = (float*)d_out;

  s4_kernel_freq<<<NH * 8, 256, 0, stream>>>(Lre, Lim, Pre, Pim, Bre, Bim, Cre, Cim, lstep);
  s4_fftconv<<<NH * (NB / 2), 512, 0, stream>>>(u, y);
}